// Round 8
// baseline (181.253 us; speedup 1.0000x reference)
//
#include <hip/hip_runtime.h>
#include <hip/hip_fp16.h>

// Reblur_Net: 3 recurrent modulated DCNv2 passes, C=O=3, K=3, B=4, H=W=512.
// out = (sharp + f1 + f2 + f3) / 4.
//
//  prep   : motion fp32 -> fp16 planar + sharp -> half4 (pure streaming).
//  pass1-3: 2D-tiled DCN. Block = 4x64 output tile. fp16 motion tile DMA'd
//           to LDS (global_load_lds); 15x75 half4 feature tile staged in LDS;
//           bilinear taps read LDS (36 ds_read_b64); rare out-of-halo taps
//           (|d|>4, P~1e-4) take the exact global fallback. Pass 3 folds the
//           4-way average. XCD-swizzled block order for L2 halo reuse.

#define HH 512
#define WW 512
#define BATCH 4
#define HWSZ (HH * WW)
#define MP 28               // fp16 motion plane stride (27 + 1 pad)
#define MBLKS (108 * 256)

#define TROWS 15            // staged tile rows   (y0-5 .. y0+9)
#define TCOLS 75            // staged tile cols   (x0-5 .. x0+69), also pitch
#define HLY 5
#define HLX 5

union U4 { uint4 u; __half2 h[4]; };
union U2 { uint2 u; __half2 h[2]; };

typedef const __attribute__((address_space(1))) void* gas_t;
typedef __attribute__((address_space(3))) void* las_t;

__global__ __launch_bounds__(256) void prep_kernel(
    const float* __restrict__ sharp, const float* __restrict__ motion,
    uint4* __restrict__ sharp16, __half* __restrict__ mot16)
{
    const int blk = blockIdx.x;
    const int t = threadIdx.x;
    if (blk < MBLKS) {
        const int P = blk >> 8;          // 0..107 = b*27+pl
        const int b = P / 27;
        const int pl = P - b * 27;
        const int off = (blk & 255) * 1024 + t * 4;
        const float4 v = *(const float4*)(motion + ((size_t)P << 18) + off);
        U2 o;
        o.h[0] = __float22half2_rn(make_float2(v.x, v.y));
        o.h[1] = __float22half2_rn(make_float2(v.z, v.w));
        *(uint2*)(mot16 + ((size_t)b * MP + pl) * HWSZ + off) = o.u;
    } else {
        const int i = (blk - MBLKS) * 256 + t;       // pair index
        const int b = i >> 17;
        const int p = (i & (HWSZ / 2 - 1)) * 2;
        const float* s = sharp + (size_t)b * 3 * HWSZ + p;
        const float2 c0 = *(const float2*)(s);
        const float2 c1 = *(const float2*)(s + HWSZ);
        const float2 c2 = *(const float2*)(s + 2 * HWSZ);
        U4 o;
        o.h[0] = __float22half2_rn(make_float2(c0.x, c1.x));
        o.h[1] = __float22half2_rn(make_float2(c2.x, 0.f));
        o.h[2] = __float22half2_rn(make_float2(c0.y, c1.y));
        o.h[3] = __float22half2_rn(make_float2(c2.y, 0.f));
        sharp16[i] = o.u;
    }
}

// LAST: fold out = (sharp + f1 + f2 + f3)/4 (pass 3).
template <bool LAST>
__global__ __launch_bounds__(256) void dcn_kernel(
    const uint2* __restrict__ src,     // [B][HWSZ] half4 px (current features)
    const __half* __restrict__ mot16,  // [B,MP,H,W] fp16
    const float* __restrict__ wgt,     // 81 floats [o][c][k]
    const float* __restrict__ bias,    // 3 floats
    uint2* __restrict__ dst,           // half4 px (if !LAST)
    const uint2* __restrict__ cS,      // sharp half4 (if LAST)
    const uint2* __restrict__ c1,      // f1 half4 (if LAST)
    float* __restrict__ out)           // [B,3,H,W] planar fp32 (if LAST)
{
    __shared__ __align__(16) __half msmem[MP * 256];   // 14336 B
    __shared__ U2 tile[TROWS * TCOLS];                 // 9000 B
    __shared__ float sw[84];

    const int t = threadIdx.x;
    int blk = blockIdx.x;
    blk = (blk & 7) * 512 + (blk >> 3);      // XCD swizzle (4096 = 8 * 512)
    const int b = blk >> 10;
    const int tid = blk & 1023;
    const int y0 = (tid >> 3) * 4;           // tile origin
    const int x0 = (tid & 7) * 64;
    const int w = t >> 6, lane = t & 63;     // w == row within tile
    const int y = y0 + w, x = x0 + lane;
    const int p = y * WW + x;

    if (t < 84) sw[t] = (t < 81) ? wgt[t] : bias[t - 81];

    // Async DMA: fp16 motion 4x64 tile, one wave per PLANE PAIR.
    // lane<32 -> plane 2q, lane>=32 -> plane 2q+1; within 32: row=l5>>3,
    // col8=(l5&7)*8. LDS layout msmem[pl][r*64+c]. Pad plane 27 never read.
    {
        const __half* mb = mot16 + (size_t)b * MP * HWSZ + y0 * WW + x0;
#pragma unroll
        for (int rr = 0; rr < 4; ++rr) {
            const int q = rr * 4 + w;
            if (q < 14) {
                const int pl = 2 * q + (lane >> 5);
                const int l5 = lane & 31;
                const __half* gsrc = mb + (size_t)pl * HWSZ + (l5 >> 3) * WW + (l5 & 7) * 8;
                __builtin_amdgcn_global_load_lds((gas_t)gsrc,
                                                 (las_t)(msmem + q * 512),
                                                 16, 0, 0);
            }
        }
    }

    // Stage the 15x75 half4 feature tile (valid region only).
    const uint2* simg = src + (size_t)b * HWSZ;
    const int rl = y0 - HLY, cl = x0 - HLX;
#pragma unroll
    for (int it = 0; it < 5; ++it) {
        const int i = t + it * 256;
        if (i < TROWS * TCOLS) {
            const int rr = i / TCOLS, cc = i - rr * TCOLS;
            const int gy = rl + rr, gx = cl + cc;
            if (gy >= 0 && gy < HH && gx >= 0 && gx < WW)
                tile[i] = *(const U2*)&simg[gy * WW + gx];
        }
    }

    // Pass-3 center values (issued before the barrier).
    U2 csv, c1v, c2v;
    if (LAST) {
        csv = *(const U2*)&cS[(size_t)b * HWSZ + p];
        c1v = *(const U2*)&c1[(size_t)b * HWSZ + p];
        c2v = *(const U2*)&simg[p];
    }

    __syncthreads();   // drains DMA (vmcnt) + ds_writes

    const char* sb = (const char*)simg;
    float acc0 = sw[81], acc1 = sw[82], acc2 = sw[83];

#pragma unroll
    for (int k = 0; k < 9; ++k) {
        const float dy = __half2float(msmem[(2 * k) * 256 + t]);
        const float dx = __half2float(msmem[(2 * k + 1) * 256 + t]);
        const float m  = __half2float(msmem[(18 + k) * 256 + t]);
        const float py = (float)(y + k / 3 - 1) + dy;
        const float px = (float)(x + k % 3 - 1) + dx;

        const float y0f = floorf(py), x0f = floorf(px);
        const float wy = py - y0f, wx = px - x0f;
        const bool vy0 = (y0f >= 0.f) && (y0f <= 511.f);
        const bool vy1 = (y0f >= -1.f) && (y0f <= 510.f);
        const bool vx0 = (x0f >= 0.f) && (x0f <= 511.f);
        const bool vx1 = (x0f >= -1.f) && (x0f <= 510.f);
        const int iy0 = (int)fminf(fmaxf(y0f, 0.f), 511.f);
        const int iy1 = (int)fminf(fmaxf(y0f + 1.f, 0.f), 511.f);
        const int ix0 = (int)fminf(fmaxf(x0f, 0.f), 511.f);
        const int ix1 = (int)fminf(fmaxf(x0f + 1.f, 0.f), 511.f);
        const int lc  = (int)fminf(fmaxf(x0f, 0.f), 510.f);
        const int s0 = ix0 - lc, s1 = ix1 - lc;

        const float w00 = (vy0 && vx0) ? (1.f - wy) * (1.f - wx) * m : 0.f;
        const float w01 = (vy0 && vx1) ? (1.f - wy) * wx * m : 0.f;
        const float w10 = (vy1 && vx0) ? wy * (1.f - wx) * m : 0.f;
        const float w11 = (vy1 && vx1) ? wy * wx * m : 0.f;
        const float wlo0 = s0 ? 0.f : (s1 ? w00 : w00 + w01);
        const float whi0 = s1 ? (s0 ? w00 + w01 : w01) : 0.f;
        const float wlo1 = s0 ? 0.f : (s1 ? w10 : w10 + w11);
        const float whi1 = s1 ? (s0 ? w10 + w11 : w11) : 0.f;

        U2 aL, aH, bL, bH;
        const bool fast = (iy0 >= rl) && (iy1 <= rl + TROWS - 1) &&
                          (lc >= cl) && (lc <= cl + TCOLS - 2);
        if (fast) {
            const int ta = (iy0 - rl) * TCOLS + (lc - cl);
            const int tb = (iy1 - rl) * TCOLS + (lc - cl);
            aL = tile[ta]; aH = tile[ta + 1];
            bL = tile[tb]; bH = tile[tb + 1];
        } else {
            U4 ra, rb;
            ra.u = *(const uint4*)(sb + (size_t)(iy0 * WW + lc) * 8);
            rb.u = *(const uint4*)(sb + (size_t)(iy1 * WW + lc) * 8);
            aL.h[0] = ra.h[0]; aL.h[1] = ra.h[1];
            aH.h[0] = ra.h[2]; aH.h[1] = ra.h[3];
            bL.h[0] = rb.h[0]; bL.h[1] = rb.h[1];
            bH.h[0] = rb.h[2]; bH.h[1] = rb.h[3];
        }

        const float2 aL01 = __half22float2(aL.h[0]);
        const float2 aL2  = __half22float2(aL.h[1]);
        const float2 aH01 = __half22float2(aH.h[0]);
        const float2 aH2  = __half22float2(aH.h[1]);
        const float2 bL01 = __half22float2(bL.h[0]);
        const float2 bL2  = __half22float2(bL.h[1]);
        const float2 bH01 = __half22float2(bH.h[0]);
        const float2 bH2  = __half22float2(bH.h[1]);

        const float v0 = wlo0 * aL01.x + whi0 * aH01.x + wlo1 * bL01.x + whi1 * bH01.x;
        const float v1 = wlo0 * aL01.y + whi0 * aH01.y + wlo1 * bL01.y + whi1 * bH01.y;
        const float v2 = wlo0 * aL2.x  + whi0 * aH2.x  + wlo1 * bL2.x  + whi1 * bH2.x;

        acc0 += sw[0 * 9 + k] * v0 + sw[1 * 9 + k] * v1 + sw[2 * 9 + k] * v2;
        acc1 += sw[3 * 9 + k] * v0 + sw[4 * 9 + k] * v1 + sw[5 * 9 + k] * v2;
        acc2 += sw[6 * 9 + k] * v0 + sw[7 * 9 + k] * v1 + sw[8 * 9 + k] * v2;
    }

    if (!LAST) {
        U2 o;
        o.h[0] = __float22half2_rn(make_float2(acc0, acc1));
        o.h[1] = __float22half2_rn(make_float2(acc2, 0.f));
        dst[(size_t)b * HWSZ + p] = o.u;
    } else {
        const float2 s01 = __half22float2(csv.h[0]);
        const float2 s2  = __half22float2(csv.h[1]);
        const float2 a01 = __half22float2(c1v.h[0]);
        const float2 a2  = __half22float2(c1v.h[1]);
        const float2 b01 = __half22float2(c2v.h[0]);
        const float2 b2  = __half22float2(c2v.h[1]);
        const size_t ob = (size_t)b * 3 * HWSZ + p;
        out[ob]            = (s01.x + a01.x + b01.x + acc0) * 0.25f;
        out[ob + HWSZ]     = (s01.y + a01.y + b01.y + acc1) * 0.25f;
        out[ob + 2 * HWSZ] = (s2.x  + a2.x  + b2.x  + acc2) * 0.25f;
    }
}

extern "C" void kernel_launch(void* const* d_in, const int* in_sizes, int n_in,
                              void* d_out, int out_size, void* d_ws, size_t ws_size,
                              hipStream_t stream) {
    const float* sharp  = (const float*)d_in[0];
    const float* motion = (const float*)d_in[1];
    const float* wts    = (const float*)d_in[2];  // 3 x 81
    const float* bias   = (const float*)d_in[3];  // 3 x 3
    float* out = (float*)d_out;

    const size_t img = (size_t)BATCH * HWSZ;
    uint2* bufS = (uint2*)d_ws;                   // 8.39 MB each
    uint2* buf1 = bufS + img;
    uint2* buf2 = buf1 + img;
    __half* mot16 = (__half*)(buf2 + img);        // 58.7 MB ([B][MP][HW])

    const dim3 block(256);
    const dim3 gridP(MBLKS + img / 512);          // 27648 + 2048
    const dim3 gridD(img / 256);                  // 4096

    prep_kernel<<<gridP, block, 0, stream>>>(sharp, motion, (uint4*)bufS, mot16);
    dcn_kernel<false><<<gridD, block, 0, stream>>>(
        bufS, mot16, wts, bias, buf1, nullptr, nullptr, nullptr);
    dcn_kernel<false><<<gridD, block, 0, stream>>>(
        buf1, mot16, wts + 81, bias + 3, buf2, nullptr, nullptr, nullptr);
    dcn_kernel<true><<<gridD, block, 0, stream>>>(
        buf2, mot16, wts + 162, bias + 6, nullptr, bufS, buf1, out);
}

// Round 9
// 130.146 us; speedup vs baseline: 1.3927x; 1.3927x over previous
//
#include <hip/hip_runtime.h>
#include <hip/hip_fp16.h>

// Reblur_Net: 3 recurrent modulated DCNv2 passes, C=O=3, K=3, B=4, H=W=512.
// out = (sharp + f1 + f2 + f3) / 4.
//
//  prep : one block per image row. Converts motion fp32 -> fp16 into a
//         block-contiguous 27.6 KB row slab [row][27][512] + sharp -> half4.
//  pass : one block per row (SAME swizzle as prep -> same XCD; slab is
//         L2-local). Slab DMA'd to LDS via global_load_lds (27 contiguous
//         wave-ops). 2 px/thread. Direct half4 feature gathers (both corners
//         of a bilinear row = one 16B dwordx4) - NO feature staging (R5/R8
//         proved staging loses). Pass 3 folds the 4-way average.
//  XCD swizzle r=(bid&7)*256+(bid>>3): XCD k owns rows [k*256, k*256+256);
//  vertical gather neighbors stay XCD-local; 1 MB features/XCD fits L2.

#define HH 512
#define WW 512
#define BATCH 4
#define HWSZ (HH * WW)
#define NROWS (BATCH * HH)          // 2048
#define MROW (27 * 512)             // halfs per motion row slab (27648 B)

union U4 { uint4 u; __half2 h[4]; };
union U2 { uint2 u; __half2 h[2]; };

typedef const __attribute__((address_space(1))) void* gas_t;
typedef __attribute__((address_space(3))) void* las_t;

__device__ __forceinline__ int swz(int bid) {   // 2048 = 8 XCD chunks x 256
    return (bid & 7) * 256 + (bid >> 3);
}

__global__ __launch_bounds__(256) void prep_kernel(
    const float* __restrict__ sharp, const float* __restrict__ motion,
    uint4* __restrict__ sharp16, __half* __restrict__ mot16)
{
    const int r = swz(blockIdx.x);          // row id: b*512 + y
    const int t = threadIdx.x;
    const int b = r >> 9;
    const int y = r & 511;

    // motion: 27 planes, fp32 row slice -> fp16 row slab [r][27][512]
    const float* msrc = motion + ((size_t)b * 27 << 18) + y * 512 + 2 * t;
    __half2* mdst = (__half2*)(mot16 + (size_t)r * MROW) + t;
#pragma unroll
    for (int pl = 0; pl < 27; ++pl) {
        const float2 v = *(const float2*)(msrc + ((size_t)pl << 18));
        mdst[pl * 256] = __float22half2_rn(v);
    }

    // sharp -> half4 px pairs (uint4 = 2 px)
    const float* s = sharp + (size_t)b * 3 * HWSZ + y * 512 + 2 * t;
    const float2 c0 = *(const float2*)(s);
    const float2 c1 = *(const float2*)(s + HWSZ);
    const float2 c2 = *(const float2*)(s + 2 * HWSZ);
    U4 o;
    o.h[0] = __float22half2_rn(make_float2(c0.x, c1.x));
    o.h[1] = __float22half2_rn(make_float2(c2.x, 0.f));
    o.h[2] = __float22half2_rn(make_float2(c0.y, c1.y));
    o.h[3] = __float22half2_rn(make_float2(c2.y, 0.f));
    sharp16[(size_t)r * 256 + t] = o.u;
}

// Bilinear sample of 3 channels at (py,px), modulation m, zero outside.
__device__ __forceinline__ void bilinear3(const char* __restrict__ sb,
                                          float py, float px, float m,
                                          float& o0, float& o1, float& o2)
{
    const float y0f = floorf(py), x0f = floorf(px);
    const float wy = py - y0f, wx = px - x0f;
    const bool vy0 = (y0f >= 0.f) && (y0f <= 511.f);
    const bool vy1 = (y0f >= -1.f) && (y0f <= 510.f);
    const bool vx0 = (x0f >= 0.f) && (x0f <= 511.f);
    const bool vx1 = (x0f >= -1.f) && (x0f <= 510.f);
    const int iy0 = (int)fminf(fmaxf(y0f, 0.f), 511.f);
    const int iy1 = (int)fminf(fmaxf(y0f + 1.f, 0.f), 511.f);
    const int ix0 = (int)fminf(fmaxf(x0f, 0.f), 511.f);
    const int ix1 = (int)fminf(fmaxf(x0f + 1.f, 0.f), 511.f);
    const int lc  = (int)fminf(fmaxf(x0f, 0.f), 510.f);   // pair base column
    const int s0 = ix0 - lc;
    const int s1 = ix1 - lc;

    const float w00 = (vy0 && vx0) ? (1.f - wy) * (1.f - wx) * m : 0.f;
    const float w01 = (vy0 && vx1) ? (1.f - wy) * wx * m : 0.f;
    const float w10 = (vy1 && vx0) ? wy * (1.f - wx) * m : 0.f;
    const float w11 = (vy1 && vx1) ? wy * wx * m : 0.f;

    // Blend corner weights onto the two loaded pixel slots (clamp-safe).
    const float wlo0 = s0 ? 0.f : (s1 ? w00 : w00 + w01);
    const float whi0 = s1 ? (s0 ? w00 + w01 : w01) : 0.f;
    const float wlo1 = s0 ? 0.f : (s1 ? w10 : w10 + w11);
    const float whi1 = s1 ? (s0 ? w10 + w11 : w11) : 0.f;

    U4 ra, rb;
    ra.u = *(const uint4*)(sb + (size_t)(iy0 * WW + lc) * 8);
    rb.u = *(const uint4*)(sb + (size_t)(iy1 * WW + lc) * 8);
    const float2 aL = __half22float2(ra.h[0]);
    const float2 aLz = __half22float2(ra.h[1]);
    const float2 aH = __half22float2(ra.h[2]);
    const float2 aHz = __half22float2(ra.h[3]);
    const float2 bL = __half22float2(rb.h[0]);
    const float2 bLz = __half22float2(rb.h[1]);
    const float2 bH = __half22float2(rb.h[2]);
    const float2 bHz = __half22float2(rb.h[3]);

    o0 = wlo0 * aL.x + whi0 * aH.x + wlo1 * bL.x + whi1 * bH.x;
    o1 = wlo0 * aL.y + whi0 * aH.y + wlo1 * bL.y + whi1 * bH.y;
    o2 = wlo0 * aLz.x + whi0 * aHz.x + wlo1 * bLz.x + whi1 * bHz.x;
}

// LAST: fold out = (sharp + f1 + f2 + f3)/4 (pass 3).
template <bool LAST>
__global__ __launch_bounds__(256) void dcn_kernel(
    const uint2* __restrict__ src,     // [B*HWSZ] half4 px (current features)
    const __half* __restrict__ mot16,  // [NROWS][27][512] fp16 row slabs
    const float* __restrict__ wgt,     // 81 floats [o][c][k]
    const float* __restrict__ bias,    // 3 floats
    uint2* __restrict__ dst,           // half4 px (if !LAST)
    const uint2* __restrict__ cS,      // sharp half4 (if LAST)
    const uint2* __restrict__ c1,      // f1 half4 (if LAST)
    float* __restrict__ out)           // [B,3,H,W] planar fp32 (if LAST)
{
    __shared__ __align__(16) __half mlds[MROW];   // 27648 B
    __shared__ float sw[84];

    const int t = threadIdx.x;
    const int r = swz(blockIdx.x);           // row id
    const int b = r >> 9;
    const int y = r & 511;
    const int w = t >> 6, lane = t & 63;
    const int p1 = r * 512 + t;              // flat px (x = t)
    const int p2 = p1 + 256;                 // flat px (x = t+256)

    if (t < 84) sw[t] = (t < 81) ? wgt[t] : bias[t - 81];

    // DMA the contiguous 27648 B motion row slab -> LDS (27 wave-ops).
    {
        const __half* mrow = mot16 + (size_t)r * MROW;
#pragma unroll
        for (int i = 0; i < 7; ++i) {
            const int c = i * 4 + w;
            if (c < 27) {
                __builtin_amdgcn_global_load_lds((gas_t)(mrow + c * 512 + lane * 8),
                                                 (las_t)(mlds + c * 512),
                                                 16, 0, 0);
            }
        }
    }

    const uint2* simg = src + ((size_t)b << 18);

    // Pass-3 center values (issued before the barrier to hide latency).
    U2 csA, c1A, c2A, csB, c1B, c2B;
    if (LAST) {
        csA = *(const U2*)&cS[p1];  csB = *(const U2*)&cS[p2];
        c1A = *(const U2*)&c1[p1];  c1B = *(const U2*)&c1[p2];
        c2A = *(const U2*)&src[p1]; c2B = *(const U2*)&src[p2];
    }

    __syncthreads();   // drains DMA (vmcnt+lgkmcnt)

    const char* sb = (const char*)simg;
    float a00 = sw[81], a01 = sw[82], a02 = sw[83];   // px A (x=t)
    float a10 = sw[81], a11 = sw[82], a12 = sw[83];   // px B (x=t+256)

#pragma unroll
    for (int k = 0; k < 9; ++k) {
        const float ky = (float)(y + k / 3 - 1);
        const float kxA = (float)(t + k % 3 - 1);
        const float kxB = kxA + 256.f;

        const float dyA = __half2float(mlds[(2 * k) * 512 + t]);
        const float dxA = __half2float(mlds[(2 * k + 1) * 512 + t]);
        const float mA  = __half2float(mlds[(18 + k) * 512 + t]);
        const float dyB = __half2float(mlds[(2 * k) * 512 + t + 256]);
        const float dxB = __half2float(mlds[(2 * k + 1) * 512 + t + 256]);
        const float mB  = __half2float(mlds[(18 + k) * 512 + t + 256]);

        float v0, v1, v2;
        bilinear3(sb, ky + dyA, kxA + dxA, mA, v0, v1, v2);
        a00 += sw[0 * 9 + k] * v0 + sw[1 * 9 + k] * v1 + sw[2 * 9 + k] * v2;
        a01 += sw[3 * 9 + k] * v0 + sw[4 * 9 + k] * v1 + sw[5 * 9 + k] * v2;
        a02 += sw[6 * 9 + k] * v0 + sw[7 * 9 + k] * v1 + sw[8 * 9 + k] * v2;

        float u0, u1, u2;
        bilinear3(sb, ky + dyB, kxB + dxB, mB, u0, u1, u2);
        a10 += sw[0 * 9 + k] * u0 + sw[1 * 9 + k] * u1 + sw[2 * 9 + k] * u2;
        a11 += sw[3 * 9 + k] * u0 + sw[4 * 9 + k] * u1 + sw[5 * 9 + k] * u2;
        a12 += sw[6 * 9 + k] * u0 + sw[7 * 9 + k] * u1 + sw[8 * 9 + k] * u2;
    }

    if (!LAST) {
        U2 oA, oB;
        oA.h[0] = __float22half2_rn(make_float2(a00, a01));
        oA.h[1] = __float22half2_rn(make_float2(a02, 0.f));
        oB.h[0] = __float22half2_rn(make_float2(a10, a11));
        oB.h[1] = __float22half2_rn(make_float2(a12, 0.f));
        dst[p1] = oA.u;
        dst[p2] = oB.u;
    } else {
        const size_t ob = (size_t)b * 3 * HWSZ + y * 512 + t;
        {
            const float2 s01 = __half22float2(csA.h[0]);
            const float2 s2  = __half22float2(csA.h[1]);
            const float2 f101 = __half22float2(c1A.h[0]);
            const float2 f12  = __half22float2(c1A.h[1]);
            const float2 f201 = __half22float2(c2A.h[0]);
            const float2 f22  = __half22float2(c2A.h[1]);
            out[ob]            = (s01.x + f101.x + f201.x + a00) * 0.25f;
            out[ob + HWSZ]     = (s01.y + f101.y + f201.y + a01) * 0.25f;
            out[ob + 2 * HWSZ] = (s2.x  + f12.x  + f22.x  + a02) * 0.25f;
        }
        {
            const float2 s01 = __half22float2(csB.h[0]);
            const float2 s2  = __half22float2(csB.h[1]);
            const float2 f101 = __half22float2(c1B.h[0]);
            const float2 f12  = __half22float2(c1B.h[1]);
            const float2 f201 = __half22float2(c2B.h[0]);
            const float2 f22  = __half22float2(c2B.h[1]);
            out[ob + 256]            = (s01.x + f101.x + f201.x + a10) * 0.25f;
            out[ob + 256 + HWSZ]     = (s01.y + f101.y + f201.y + a11) * 0.25f;
            out[ob + 256 + 2 * HWSZ] = (s2.x  + f12.x  + f22.x  + a12) * 0.25f;
        }
    }
}

extern "C" void kernel_launch(void* const* d_in, const int* in_sizes, int n_in,
                              void* d_out, int out_size, void* d_ws, size_t ws_size,
                              hipStream_t stream) {
    const float* sharp  = (const float*)d_in[0];
    const float* motion = (const float*)d_in[1];
    const float* wts    = (const float*)d_in[2];  // 3 x 81
    const float* bias   = (const float*)d_in[3];  // 3 x 3
    float* out = (float*)d_out;

    const size_t img = (size_t)BATCH * HWSZ;
    __half* mot16 = (__half*)d_ws;                 // 56.6 MB (16B-aligned base)
    uint2* bufS = (uint2*)(mot16 + (size_t)NROWS * MROW);   // 8.39 MB each
    uint2* buf1 = bufS + img;
    uint2* buf2 = buf1 + img;

    const dim3 block(256);
    const dim3 grid(NROWS);                        // 2048, one block per row

    prep_kernel<<<grid, block, 0, stream>>>(sharp, motion, (uint4*)bufS, mot16);
    dcn_kernel<false><<<grid, block, 0, stream>>>(
        bufS, mot16, wts, bias, buf1, nullptr, nullptr, nullptr);
    dcn_kernel<false><<<grid, block, 0, stream>>>(
        buf1, mot16, wts + 81, bias + 3, buf2, nullptr, nullptr, nullptr);
    dcn_kernel<true><<<grid, block, 0, stream>>>(
        buf2, mot16, wts + 162, bias + 6, nullptr, bufS, buf1, out);
}

// Round 11
// 125.942 us; speedup vs baseline: 1.4392x; 1.0334x over previous
//
#include <hip/hip_runtime.h>
#include <hip/hip_fp16.h>

// Reblur_Net: 3 recurrent modulated DCNv2 passes, C=O=3, K=3, B=4, H=W=512.
// out = (sharp + f1 + f2 + f3) / 4.
//
//  prep   : grid-stride streaming kernel. motion fp32 -> fp16 planar (32B
//           read / 16B write per thread-iter, deep ILP) + sharp -> half4.
//  pass1-3: identical DCN kernels (R7-verbatim, proven correct): fp16 motion
//           strip DMA'd to LDS via global_load_lds; direct half4 feature
//           gathers (both corners of a bilinear row = one 16B dwordx4);
//           NO feature staging (R5/R8/R10 all lost). Pass 3 folds the
//           4-way average.

#define HH 512
#define WW 512
#define BATCH 4
#define HWSZ (HH * WW)
#define MP 28                      // fp16 motion plane stride (27 + 1 pad)
#define NMG (BATCH * 27 * HWSZ / 8)  // motion groups of 8 floats = 3,538,944
#define MTHREADS (2048 * 256)

union U4 { uint4 u; __half2 h[4]; };
union U2 { uint2 u; __half2 h[2]; };

typedef const __attribute__((address_space(1))) void* gas_t;
typedef __attribute__((address_space(3))) void* las_t;

__global__ __launch_bounds__(256) void prep_kernel(
    const float* __restrict__ sharp, const float* __restrict__ motion,
    uint4* __restrict__ sharp16, __half* __restrict__ mot16)
{
    const int t = threadIdx.x;
    const int blk = blockIdx.x;
    if (blk < 2048) {
        // motion fp32 [B*27][HWSZ] -> fp16 [B][MP][HWSZ], 8 floats/iter.
        for (int g = blk * 256 + t; g < NMG; g += MTHREADS) {
            const int P = g >> 15;               // plane id: b*27+pl
            const int off = (g & 32767) * 8;
            const int b = P / 27;
            const int pl = P - b * 27;
            const float* s = motion + ((size_t)P << 18) + off;
            const float4 v0 = *(const float4*)(s);
            const float4 v1 = *(const float4*)(s + 4);
            U4 o;
            o.h[0] = __float22half2_rn(make_float2(v0.x, v0.y));
            o.h[1] = __float22half2_rn(make_float2(v0.z, v0.w));
            o.h[2] = __float22half2_rn(make_float2(v1.x, v1.y));
            o.h[3] = __float22half2_rn(make_float2(v1.z, v1.w));
            *(uint4*)(mot16 + ((size_t)b * MP + pl) * HWSZ + off) = o.u;
        }
    } else {
        // sharp [B,3,H,W] fp32 -> half4 px pairs.
        const int i = (blk - 2048) * 256 + t;    // pair index, 524288 total
        const int b = i >> 17;
        const int p = (i & (HWSZ / 2 - 1)) * 2;
        const float* s = sharp + (size_t)b * 3 * HWSZ + p;
        const float2 c0 = *(const float2*)(s);
        const float2 c1 = *(const float2*)(s + HWSZ);
        const float2 c2 = *(const float2*)(s + 2 * HWSZ);
        U4 o;
        o.h[0] = __float22half2_rn(make_float2(c0.x, c1.x));
        o.h[1] = __float22half2_rn(make_float2(c2.x, 0.f));
        o.h[2] = __float22half2_rn(make_float2(c0.y, c1.y));
        o.h[3] = __float22half2_rn(make_float2(c2.y, 0.f));
        sharp16[i] = o.u;
    }
}

// Bilinear sample of 3 channels at (py,px), modulation m, zero outside.
__device__ __forceinline__ void bilinear3(const char* __restrict__ sb,
                                          float py, float px, float m,
                                          float& o0, float& o1, float& o2)
{
    const float y0f = floorf(py), x0f = floorf(px);
    const float wy = py - y0f, wx = px - x0f;
    const bool vy0 = (y0f >= 0.f) && (y0f <= 511.f);
    const bool vy1 = (y0f >= -1.f) && (y0f <= 510.f);
    const bool vx0 = (x0f >= 0.f) && (x0f <= 511.f);
    const bool vx1 = (x0f >= -1.f) && (x0f <= 510.f);
    const int iy0 = (int)fminf(fmaxf(y0f, 0.f), 511.f);
    const int iy1 = (int)fminf(fmaxf(y0f + 1.f, 0.f), 511.f);
    const int ix0 = (int)fminf(fmaxf(x0f, 0.f), 511.f);
    const int ix1 = (int)fminf(fmaxf(x0f + 1.f, 0.f), 511.f);
    const int lc  = (int)fminf(fmaxf(x0f, 0.f), 510.f);   // pair base column
    const int s0 = ix0 - lc;
    const int s1 = ix1 - lc;

    const float w00 = (vy0 && vx0) ? (1.f - wy) * (1.f - wx) * m : 0.f;
    const float w01 = (vy0 && vx1) ? (1.f - wy) * wx * m : 0.f;
    const float w10 = (vy1 && vx0) ? wy * (1.f - wx) * m : 0.f;
    const float w11 = (vy1 && vx1) ? wy * wx * m : 0.f;

    // Blend corner weights onto the two loaded pixel slots (clamp-safe).
    const float wlo0 = s0 ? 0.f : (s1 ? w00 : w00 + w01);
    const float whi0 = s1 ? (s0 ? w00 + w01 : w01) : 0.f;
    const float wlo1 = s0 ? 0.f : (s1 ? w10 : w10 + w11);
    const float whi1 = s1 ? (s0 ? w10 + w11 : w11) : 0.f;

    U4 ra, rb;
    ra.u = *(const uint4*)(sb + (size_t)(iy0 * WW + lc) * 8);
    rb.u = *(const uint4*)(sb + (size_t)(iy1 * WW + lc) * 8);
    const float2 aL = __half22float2(ra.h[0]);
    const float2 aLz = __half22float2(ra.h[1]);
    const float2 aH = __half22float2(ra.h[2]);
    const float2 aHz = __half22float2(ra.h[3]);
    const float2 bL = __half22float2(rb.h[0]);
    const float2 bLz = __half22float2(rb.h[1]);
    const float2 bH = __half22float2(rb.h[2]);
    const float2 bHz = __half22float2(rb.h[3]);

    o0 = wlo0 * aL.x + whi0 * aH.x + wlo1 * bL.x + whi1 * bH.x;
    o1 = wlo0 * aL.y + whi0 * aH.y + wlo1 * bL.y + whi1 * bH.y;
    o2 = wlo0 * aLz.x + whi0 * aHz.x + wlo1 * bLz.x + whi1 * bHz.x;
}

// LAST: fold out = (sharp + f1 + f2 + f3)/4 (pass 3).
template <bool LAST>
__global__ __launch_bounds__(256) void dcn_kernel(
    const uint2* __restrict__ src,     // [B][HWSZ] half4 px (current features)
    const __half* __restrict__ mot16,  // [B,MP,H,W] fp16
    const float* __restrict__ wgt,     // 81 floats [o][c][k]
    const float* __restrict__ bias,    // 3 floats
    uint2* __restrict__ dst,           // half4 px (if !LAST)
    const uint2* __restrict__ cS,      // sharp half4 (if LAST)
    const uint2* __restrict__ c1,      // f1 half4 (if LAST)
    float* __restrict__ out)           // [B,3,H,W] planar fp32 (if LAST)
{
    __shared__ __align__(16) char msmem[MP * 256 * 2];   // 14336 B
    __shared__ float sw[84];

    const int t = threadIdx.x;
    const int blk = blockIdx.x;              // 4096
    const int b = blk >> 10;
    const int pbase = (blk & 1023) * 256;    // strip start within image
    const int y = pbase >> 9;
    const int x = (pbase & 511) + t;
    const int p = pbase + t;
    const int w = t >> 6, lane = t & 63;

    if (t < 84) sw[t] = (t < 81) ? wgt[t] : bias[t - 81];

    // Async DMA: fp16 motion strip -> LDS. One wave per PLANE PAIR
    // (lanes 0..31 -> plane 2q, lanes 32..63 -> plane 2q+1; 1024B/pair).
    // Pair q=13 touches pad plane 27 (allocated, never read).
    {
        const __half* mbase = mot16 + (size_t)b * MP * HWSZ + pbase;
#pragma unroll
        for (int r = 0; r < 4; ++r) {
            const int q = r * 4 + w;
            if (q < 14) {
                const int pl = 2 * q + (lane >> 5);
                const __half* gsrc = mbase + (size_t)pl * HWSZ + (lane & 31) * 8;
                __builtin_amdgcn_global_load_lds((gas_t)gsrc,
                                                 (las_t)(msmem + q * 1024),
                                                 16, 0, 0);
            }
        }
    }

    const uint2* simg = src + (size_t)b * HWSZ;

    // Pass-3 center values (issued before the barrier to hide latency).
    U2 csv, c1v, c2v;
    if (LAST) {
        csv = *(const U2*)&cS[(size_t)b * HWSZ + p];
        c1v = *(const U2*)&c1[(size_t)b * HWSZ + p];
        c2v = *(const U2*)&simg[p];
    }

    __syncthreads();   // drains DMA (vmcnt+lgkmcnt)

    const char* sb = (const char*)simg;
    const __half* mh = (const __half*)msmem;
    float acc0 = sw[81], acc1 = sw[82], acc2 = sw[83];

#pragma unroll
    for (int k = 0; k < 9; ++k) {
        const float dy = __half2float(mh[(2 * k) * 256 + t]);
        const float dx = __half2float(mh[(2 * k + 1) * 256 + t]);
        const float m  = __half2float(mh[(18 + k) * 256 + t]);
        const float py = (float)(y + k / 3 - 1) + dy;
        const float px = (float)(x + k % 3 - 1) + dx;

        float v0, v1, v2;
        bilinear3(sb, py, px, m, v0, v1, v2);
        acc0 += sw[0 * 9 + k] * v0 + sw[1 * 9 + k] * v1 + sw[2 * 9 + k] * v2;
        acc1 += sw[3 * 9 + k] * v0 + sw[4 * 9 + k] * v1 + sw[5 * 9 + k] * v2;
        acc2 += sw[6 * 9 + k] * v0 + sw[7 * 9 + k] * v1 + sw[8 * 9 + k] * v2;
    }

    if (!LAST) {
        U2 o;
        o.h[0] = __float22half2_rn(make_float2(acc0, acc1));
        o.h[1] = __float22half2_rn(make_float2(acc2, 0.f));
        dst[(size_t)b * HWSZ + p] = o.u;
    } else {
        const float2 s01 = __half22float2(csv.h[0]);
        const float2 s2  = __half22float2(csv.h[1]);
        const float2 a01 = __half22float2(c1v.h[0]);
        const float2 a2  = __half22float2(c1v.h[1]);
        const float2 b01 = __half22float2(c2v.h[0]);
        const float2 b2  = __half22float2(c2v.h[1]);
        const size_t ob = (size_t)b * 3 * HWSZ + p;
        out[ob]            = (s01.x + a01.x + b01.x + acc0) * 0.25f;
        out[ob + HWSZ]     = (s01.y + a01.y + b01.y + acc1) * 0.25f;
        out[ob + 2 * HWSZ] = (s2.x  + a2.x  + b2.x  + acc2) * 0.25f;
    }
}

extern "C" void kernel_launch(void* const* d_in, const int* in_sizes, int n_in,
                              void* d_out, int out_size, void* d_ws, size_t ws_size,
                              hipStream_t stream) {
    const float* sharp  = (const float*)d_in[0];
    const float* motion = (const float*)d_in[1];
    const float* wts    = (const float*)d_in[2];  // 3 x 81
    const float* bias   = (const float*)d_in[3];  // 3 x 3
    float* out = (float*)d_out;

    const size_t img = (size_t)BATCH * HWSZ;
    uint2* bufS = (uint2*)d_ws;                   // 8.39 MB each
    uint2* buf1 = bufS + img;
    uint2* buf2 = buf1 + img;
    __half* mot16 = (__half*)(buf2 + img);        // 58.7 MB ([B][MP][HW])

    const dim3 block(256);
    const dim3 gridP(4096);                       // 2048 motion + 2048 sharp
    const dim3 gridD(img / 256);                  // 4096

    prep_kernel<<<gridP, block, 0, stream>>>(sharp, motion, (uint4*)bufS, mot16);
    dcn_kernel<false><<<gridD, block, 0, stream>>>(
        bufS, mot16, wts, bias, buf1, nullptr, nullptr, nullptr);
    dcn_kernel<false><<<gridD, block, 0, stream>>>(
        buf1, mot16, wts + 81, bias + 3, buf2, nullptr, nullptr, nullptr);
    dcn_kernel<true><<<gridD, block, 0, stream>>>(
        buf2, mot16, wts + 162, bias + 6, nullptr, bufS, buf1, out);
}